// Round 1
// baseline (2701.884 us; speedup 1.0000x reference)
//
#include <hip/hip_runtime.h>

#define TPB 256

static constexpr int kBN   = 737280;   // B*T*V*H*W
static constexpr int kSlab = 92160;    // V*H*W
static constexpr int kNT   = 512;      // NUM_TRACKS
static constexpr int kNSeg = 4096;     // (B*T)*NUM_TRACKS

// monotone float <-> unsigned key for atomic max on floats
__device__ __forceinline__ unsigned fkey(float f) {
    unsigned b = __float_as_uint(f);
    return (b & 0x80000000u) ? ~b : (b | 0x80000000u);
}
__device__ __forceinline__ float keyf(unsigned k) {
    unsigned b = (k & 0x80000000u) ? (k & 0x7fffffffu) : ~k;
    return __uint_as_float(b);
}

// dup && dist<=THR gate; deterministic — recomputed identically in k_max2/k_sum2/k_out
__device__ __forceinline__ bool elem_active(int i, int id,
                                            const int* __restrict__ cnt,
                                            const float* __restrict__ center,
                                            const float* __restrict__ z1,
                                            const float* __restrict__ sec,
                                            int& seg) {
    if (id < 0) return false;
    seg = (i / kSlab) * kNT + id;
    if (cnt[seg] < 2) return false;
    float inv = 1.0f / fmaxf(z1[seg], 1e-20f);
    float d0 = center[3 * i + 0] - sec[3 * seg + 0] * inv;
    float d1 = center[3 * i + 1] - sec[3 * seg + 1] * inv;
    float d2 = center[3 * i + 2] - sec[3 * seg + 2] * inv;
    float dist = sqrtf(d0 * d0 + d1 * d1 + d2 * d2);
    return dist <= 2.0f;
}

__global__ void k_count(const int* __restrict__ gid, int* cnt) {
    int i = blockIdx.x * TPB + threadIdx.x;
    if (i >= kBN) return;
    int id = gid[i];
    if (id >= 0) atomicAdd(&cnt[(i / kSlab) * kNT + id], 1);
}

__global__ void k_max1(const int* __restrict__ gid, const int* __restrict__ cnt,
                       const float* __restrict__ keep, unsigned* mk1) {
    int i = blockIdx.x * TPB + threadIdx.x;
    if (i >= kBN) return;
    int id = gid[i];
    if (id < 0) return;
    int seg = (i / kSlab) * kNT + id;
    if (cnt[seg] < 2) return;
    atomicMax(&mk1[seg], fkey(keep[i]));
}

__global__ void k_sum1(const int* __restrict__ gid, const int* __restrict__ cnt,
                       const float* __restrict__ keep, const float* __restrict__ center,
                       const unsigned* __restrict__ mk1, float* z1, float* sec) {
    int i = blockIdx.x * TPB + threadIdx.x;
    if (i >= kBN) return;
    int id = gid[i];
    if (id < 0) return;
    int seg = (i / kSlab) * kNT + id;
    if (cnt[seg] < 2) return;
    float m1 = keyf(mk1[seg]);
    float e = expf(keep[i] - m1);
    atomicAdd(&z1[seg], e);
    atomicAdd(&sec[3 * seg + 0], e * center[3 * i + 0]);
    atomicAdd(&sec[3 * seg + 1], e * center[3 * i + 1]);
    atomicAdd(&sec[3 * seg + 2], e * center[3 * i + 2]);
}

__global__ void k_max2(const int* __restrict__ gid, const int* __restrict__ cnt,
                       const float* __restrict__ keep, const float* __restrict__ center,
                       const float* __restrict__ z1, const float* __restrict__ sec,
                       unsigned* mk2) {
    int i = blockIdx.x * TPB + threadIdx.x;
    if (i >= kBN) return;
    int id = gid[i];
    int seg;
    if (!elem_active(i, id, cnt, center, z1, sec, seg)) return;
    atomicMax(&mk2[seg], fkey(keep[i]));
}

__global__ void k_sum2(const int* __restrict__ gid, const int* __restrict__ cnt,
                       const float* __restrict__ keep, const float* __restrict__ center,
                       const float* __restrict__ offset, const float* __restrict__ opacity,
                       const float* __restrict__ scale, const float* __restrict__ rot,
                       const float* __restrict__ fd, const float* __restrict__ inst,
                       const float* __restrict__ motion,
                       const float* __restrict__ z1, const float* __restrict__ sec,
                       const unsigned* __restrict__ mk2,
                       float* z2, float* sums, int* rep) {
    int i = blockIdx.x * TPB + threadIdx.x;
    if (i >= kBN) return;
    int id = gid[i];
    int seg;
    if (!elem_active(i, id, cnt, center, z1, sec, seg)) return;
    float k0 = keep[i];
    float m2 = keyf(mk2[seg]);
    float e = expf(k0 - m2);
    atomicAdd(&z2[seg], e);
    float* s = &sums[seg * 65];
#pragma unroll
    for (int c = 0; c < 3; c++) atomicAdd(&s[c], e * center[3 * i + c]);
#pragma unroll
    for (int c = 0; c < 3; c++) atomicAdd(&s[3 + c], e * offset[3 * i + c]);
    atomicAdd(&s[6], e * opacity[i]);
#pragma unroll
    for (int c = 0; c < 3; c++) atomicAdd(&s[7 + c], e * scale[3 * i + c]);
#pragma unroll
    for (int c = 0; c < 4; c++) atomicAdd(&s[10 + c], e * rot[4 * i + c]);
#pragma unroll
    for (int c = 0; c < 3; c++) atomicAdd(&s[14 + c], e * fd[3 * i + c]);
#pragma unroll
    for (int c = 0; c < 32; c++) atomicAdd(&s[17 + c], e * inst[32 * i + c]);
#pragma unroll
    for (int c = 0; c < 16; c++) atomicAdd(&s[49 + c], e * motion[16 * i + c]);
    if (k0 == m2) atomicMin(&rep[seg], i);
}

__global__ void k_out(const int* __restrict__ gid, const int* __restrict__ cnt,
                      const float* __restrict__ keep, const float* __restrict__ center,
                      const float* __restrict__ offset, const float* __restrict__ opacity,
                      const float* __restrict__ scale, const float* __restrict__ rot,
                      const float* __restrict__ fd, const float* __restrict__ inst,
                      const float* __restrict__ motion,
                      const float* __restrict__ z1, const float* __restrict__ sec,
                      const unsigned* __restrict__ mk2,
                      const float* __restrict__ z2, const float* __restrict__ sums,
                      const int* __restrict__ rep, float* __restrict__ out) {
    int i = blockIdx.x * TPB + threadIdx.x;
    if (i >= kBN) return;
    int id = gid[i];
    float* o = out + (long)i * 66;
    int seg;
    if (elem_active(i, id, cnt, center, z1, sec, seg)) {
        float m2 = keyf(mk2[seg]);
        float inv = 1.0f / fmaxf(z2[seg], 1e-20f);
        float sfac = (i == rep[seg]) ? 1.0f : 0.05f;
        const float* s = &sums[seg * 65];
#pragma unroll
        for (int c = 0; c < 3; c++) o[c] = s[c] * inv;          // center
#pragma unroll
        for (int c = 0; c < 3; c++) o[3 + c] = s[3 + c] * inv;  // offset
        o[6] = s[6] * inv * sfac;                               // opacity
#pragma unroll
        for (int c = 0; c < 3; c++) o[7 + c] = s[7 + c] * inv;  // scale
        float q0 = s[10] * inv, q1 = s[11] * inv, q2 = s[12] * inv, q3 = s[13] * inv;
        float nrm = sqrtf(q0 * q0 + q1 * q1 + q2 * q2 + q3 * q3);
        float rn = 1.0f / fmaxf(nrm, 1e-12f);
        o[10] = q0 * rn; o[11] = q1 * rn; o[12] = q2 * rn; o[13] = q3 * rn;  // rotation
#pragma unroll
        for (int c = 0; c < 3; c++) o[14 + c] = s[14 + c] * inv;  // feat_dc
        o[17] = m2 * sfac;                                        // keep (mkeep == m2)
#pragma unroll
        for (int c = 0; c < 32; c++) o[18 + c] = s[17 + c] * inv; // inst
#pragma unroll
        for (int c = 0; c < 16; c++) o[50 + c] = s[49 + c] * inv; // motion
    } else {
#pragma unroll
        for (int c = 0; c < 3; c++) o[c] = center[3 * i + c];
#pragma unroll
        for (int c = 0; c < 3; c++) o[3 + c] = offset[3 * i + c];
        o[6] = opacity[i];
#pragma unroll
        for (int c = 0; c < 3; c++) o[7 + c] = scale[3 * i + c];
#pragma unroll
        for (int c = 0; c < 4; c++) o[10 + c] = rot[4 * i + c];
#pragma unroll
        for (int c = 0; c < 3; c++) o[14 + c] = fd[3 * i + c];
        o[17] = keep[i];
#pragma unroll
        for (int c = 0; c < 32; c++) o[18 + c] = inst[32 * i + c];
#pragma unroll
        for (int c = 0; c < 16; c++) o[50 + c] = motion[16 * i + c];
    }
}

extern "C" void kernel_launch(void* const* d_in, const int* in_sizes, int n_in,
                              void* d_out, int out_size, void* d_ws, size_t ws_size,
                              hipStream_t stream) {
    const float* center = (const float*)d_in[0];
    const float* offset = (const float*)d_in[1];
    const float* opacity = (const float*)d_in[2];
    const float* scale = (const float*)d_in[3];
    const float* rot = (const float*)d_in[4];
    const float* fd = (const float*)d_in[5];
    const float* keep = (const float*)d_in[6];
    const float* inst = (const float*)d_in[7];
    const float* motion = (const float*)d_in[8];
    const int* gid = (const int*)d_in[9];
    float* out = (float*)d_out;

    // workspace layout (4-byte units):
    // [0,4096)        cnt        (int)
    // [4096,8192)     mk1        (unsigned key of segment max #1)
    // [8192,12288)    z1
    // [12288,24576)   sec        (3 * 4096, sum e*center)
    // [24576,28672)   mk2
    // [28672,32768)   z2
    // [32768,299008)  sums       (65 * 4096)
    // [299008,303104) rep        (int, init 0x7F7F7F7F > BN)
    int* cnt = (int*)d_ws;
    unsigned* mk1 = (unsigned*)d_ws + 4096;
    float* z1 = (float*)d_ws + 8192;
    float* sec = (float*)d_ws + 12288;
    unsigned* mk2 = (unsigned*)d_ws + 24576;
    float* z2 = (float*)d_ws + 28672;
    float* sums = (float*)d_ws + 32768;
    int* rep = (int*)d_ws + 299008;

    hipMemsetAsync(d_ws, 0, (size_t)299008 * 4, stream);
    hipMemsetAsync((char*)d_ws + (size_t)299008 * 4, 0x7F, (size_t)4096 * 4, stream);

    dim3 grid(kBN / TPB), block(TPB);
    k_count<<<grid, block, 0, stream>>>(gid, cnt);
    k_max1<<<grid, block, 0, stream>>>(gid, cnt, keep, mk1);
    k_sum1<<<grid, block, 0, stream>>>(gid, cnt, keep, center, mk1, z1, sec);
    k_max2<<<grid, block, 0, stream>>>(gid, cnt, keep, center, z1, sec, mk2);
    k_sum2<<<grid, block, 0, stream>>>(gid, cnt, keep, center, offset, opacity, scale, rot,
                                       fd, inst, motion, z1, sec, mk2, z2, sums, rep);
    k_out<<<grid, block, 0, stream>>>(gid, cnt, keep, center, offset, opacity, scale, rot,
                                      fd, inst, motion, z1, sec, mk2, z2, sums, rep, out);
}

// Round 2
// 750.012 us; speedup vs baseline: 3.6025x; 3.6025x over previous
//
#include <hip/hip_runtime.h>

static constexpr int kBN   = 737280;   // B*T*V*H*W
static constexpr int kSlab = 92160;    // V*H*W
static constexpr int kNT   = 512;      // NUM_TRACKS
static constexpr int kNSeg = 4096;     // (B*T)*NUM_TRACKS
static constexpr int kChunk = 5120;    // elements per count/fill block (18 per slab, single bt)

// ---------------- count (LDS-privatized histogram) ----------------
__global__ __launch_bounds__(1024) void k_count(const int* __restrict__ gid, int* cnt) {
    __shared__ int h[kNT];
    int tid = threadIdx.x;
    if (tid < kNT) h[tid] = 0;
    __syncthreads();
    int chunk0 = blockIdx.x * kChunk;
    int bt = chunk0 / kSlab;            // chunk never straddles a slab (92160 = 18*5120)
    for (int j = tid; j < kChunk; j += 1024) {
        int id = gid[chunk0 + j];
        if (id >= 0) atomicAdd(&h[id], 1);
    }
    __syncthreads();
    if (tid < kNT) { int v = h[tid]; if (v) atomicAdd(&cnt[bt * kNT + tid], v); }
}

// ---------------- exclusive scan of 4096 counts (single block) ----------------
__global__ __launch_bounds__(1024) void k_scan(const int* __restrict__ cnt, int* offs, int* cursor) {
    __shared__ int part[1024];
    int tid = threadIdx.x;
    int b = tid * 4;
    int v0 = cnt[b], v1 = cnt[b + 1], v2 = cnt[b + 2], v3 = cnt[b + 3];
    int s01 = v0 + v1, s = s01 + v2 + v3;
    part[tid] = s;
    __syncthreads();
    for (int off = 1; off < 1024; off <<= 1) {
        int t = (tid >= off) ? part[tid - off] : 0;
        __syncthreads();
        part[tid] += t;
        __syncthreads();
    }
    int base = part[tid] - s;           // exclusive prefix of this thread's group of 4
    int o0 = base, o1 = base + v0, o2 = base + s01, o3 = base + s01 + v2;
    offs[b] = o0; offs[b + 1] = o1; offs[b + 2] = o2; offs[b + 3] = o3;
    cursor[b] = o0; cursor[b + 1] = o1; cursor[b + 2] = o2; cursor[b + 3] = o3;
}

// ---------------- fill per-segment index lists (privatized) ----------------
__global__ __launch_bounds__(1024) void k_fill(const int* __restrict__ gid, int* cursor, int* lists) {
    __shared__ int lcnt[kNT];
    __shared__ int lbase[kNT];
    int tid = threadIdx.x;
    if (tid < kNT) lcnt[tid] = 0;
    __syncthreads();
    int chunk0 = blockIdx.x * kChunk;
    int bt = chunk0 / kSlab;
    int rank[5], ids[5];
#pragma unroll
    for (int u = 0; u < 5; u++) {
        int id = gid[chunk0 + tid + u * 1024];
        ids[u] = id;
        rank[u] = (id >= 0) ? atomicAdd(&lcnt[id], 1) : 0;
    }
    __syncthreads();
    if (tid < kNT) { int c = lcnt[tid]; lbase[tid] = c ? atomicAdd(&cursor[bt * kNT + tid], c) : 0; }
    __syncthreads();
#pragma unroll
    for (int u = 0; u < 5; u++) {
        int id = ids[u];
        if (id >= 0) lists[lbase[id] + rank[u]] = chunk0 + tid + u * 1024;
    }
}

// ---------------- per-segment merge: one block per segment ----------------
__global__ __launch_bounds__(256) void k_seg(
        const int* __restrict__ lists, const int* __restrict__ offs, const int* __restrict__ cnt,
        const float* __restrict__ keep, const float* __restrict__ center,
        const float* __restrict__ offsetp, const float* __restrict__ opacity,
        const float* __restrict__ scale, const float* __restrict__ rot,
        const float* __restrict__ fd, const float* __restrict__ inst,
        const float* __restrict__ motion,
        float* __restrict__ mc1g, float* __restrict__ m2g, int* __restrict__ repg,
        float* __restrict__ merged) {
    int s = blockIdx.x;
    int n = cnt[s];
    if (n < 2) return;                  // not dup: untouched, k_out passes through
    int base = offs[s];
    int tid = threadIdx.x;

    __shared__ float red[256];
    __shared__ int redi[256];
    __shared__ float acc[66];
    __shared__ float bro[8];            // broadcast slots

    auto rmax = [&](float v) -> float {
        red[tid] = v; __syncthreads();
        for (int o = 128; o; o >>= 1) { if (tid < o) red[tid] = fmaxf(red[tid], red[tid + o]); __syncthreads(); }
        float r = red[0]; __syncthreads(); return r;
    };
    auto rsum = [&](float v) -> float {
        red[tid] = v; __syncthreads();
        for (int o = 128; o; o >>= 1) { if (tid < o) red[tid] += red[tid + o]; __syncthreads(); }
        float r = red[0]; __syncthreads(); return r;
    };

    // ---- softmax #1 max ----
    float lmax = -1e30f;
    for (int j = tid; j < n; j += 256) lmax = fmaxf(lmax, keep[lists[base + j]]);
    float m1 = rmax(lmax);

    // ---- z1 and weighted center sum -> mc1 ----
    float lz = 0.f, l0 = 0.f, l1 = 0.f, l2 = 0.f;
    for (int j = tid; j < n; j += 256) {
        int i = lists[base + j];
        float e = expf(keep[i] - m1);
        lz += e;
        l0 += e * center[3 * i + 0];
        l1 += e * center[3 * i + 1];
        l2 += e * center[3 * i + 2];
    }
    float z1 = rsum(lz);
    float c0 = rsum(l0), c1 = rsum(l1), c2 = rsum(l2);
    float inv1 = 1.0f / fmaxf(z1, 1e-20f);
    float mc0 = c0 * inv1, mcy = c1 * inv1, mcz = c2 * inv1;

    // ---- softmax #2 max over active ----
    float lm2 = -1e30f;
    for (int j = tid; j < n; j += 256) {
        int i = lists[base + j];
        float d0 = center[3 * i + 0] - mc0;
        float d1 = center[3 * i + 1] - mcy;
        float d2 = center[3 * i + 2] - mcz;
        if (sqrtf(d0 * d0 + d1 * d1 + d2 * d2) <= 2.0f) lm2 = fmaxf(lm2, keep[i]);
    }
    float m2 = rmax(lm2);

    // ---- z2, rep, 65-channel weighted sums (LDS atomics) ----
    if (tid < 66) acc[tid] = 0.f;
    __syncthreads();
    float lz2 = 0.f;
    int lrep = 0x7fffffff;
    for (int j = tid; j < n; j += 256) {
        int i = lists[base + j];
        float cx = center[3 * i + 0], cy = center[3 * i + 1], cz = center[3 * i + 2];
        float d0 = cx - mc0, d1 = cy - mcy, d2 = cz - mcz;
        if (sqrtf(d0 * d0 + d1 * d1 + d2 * d2) <= 2.0f) {
            float k0 = keep[i];
            float e = expf(k0 - m2);
            lz2 += e;
            if (k0 == m2) lrep = min(lrep, i);
            atomicAdd(&acc[0], e * cx);
            atomicAdd(&acc[1], e * cy);
            atomicAdd(&acc[2], e * cz);
#pragma unroll
            for (int c = 0; c < 3; c++) atomicAdd(&acc[3 + c], e * offsetp[3 * i + c]);
            atomicAdd(&acc[6], e * opacity[i]);
#pragma unroll
            for (int c = 0; c < 3; c++) atomicAdd(&acc[7 + c], e * scale[3 * i + c]);
            float4 r4 = *(const float4*)(rot + 4 * i);
            atomicAdd(&acc[10], e * r4.x); atomicAdd(&acc[11], e * r4.y);
            atomicAdd(&acc[12], e * r4.z); atomicAdd(&acc[13], e * r4.w);
#pragma unroll
            for (int c = 0; c < 3; c++) atomicAdd(&acc[14 + c], e * fd[3 * i + c]);
            const float4* ip = (const float4*)(inst + 32 * i);
#pragma unroll
            for (int q = 0; q < 8; q++) {
                float4 v = ip[q];
                atomicAdd(&acc[17 + 4 * q + 0], e * v.x);
                atomicAdd(&acc[17 + 4 * q + 1], e * v.y);
                atomicAdd(&acc[17 + 4 * q + 2], e * v.z);
                atomicAdd(&acc[17 + 4 * q + 3], e * v.w);
            }
            const float4* mp = (const float4*)(motion + 16 * i);
#pragma unroll
            for (int q = 0; q < 4; q++) {
                float4 v = mp[q];
                atomicAdd(&acc[49 + 4 * q + 0], e * v.x);
                atomicAdd(&acc[49 + 4 * q + 1], e * v.y);
                atomicAdd(&acc[49 + 4 * q + 2], e * v.z);
                atomicAdd(&acc[49 + 4 * q + 3], e * v.w);
            }
        }
    }
    float z2 = rsum(lz2);
    redi[tid] = lrep; __syncthreads();
    for (int o = 128; o; o >>= 1) { if (tid < o) redi[tid] = min(redi[tid], redi[tid + o]); __syncthreads(); }
    int rep = redi[0];
    __syncthreads();

    if (tid == 0) {
        float inv2 = 1.0f / fmaxf(z2, 1e-20f);
        mc1g[3 * s + 0] = mc0; mc1g[3 * s + 1] = mcy; mc1g[3 * s + 2] = mcz;
        m2g[s] = m2;
        repg[s] = rep;
        float* m = merged + (long)s * 66;
#pragma unroll
        for (int c = 0; c < 6; c++) m[c] = acc[c] * inv2;            // center, offset
        m[6] = acc[6] * inv2;                                        // opacity (pre-sfac)
#pragma unroll
        for (int c = 0; c < 3; c++) m[7 + c] = acc[7 + c] * inv2;    // scale
        float q0 = acc[10] * inv2, q1 = acc[11] * inv2, q2 = acc[12] * inv2, q3 = acc[13] * inv2;
        float nrm = sqrtf(q0 * q0 + q1 * q1 + q2 * q2 + q3 * q3);
        float rn = 1.0f / fmaxf(nrm, 1e-12f);
        m[10] = q0 * rn; m[11] = q1 * rn; m[12] = q2 * rn; m[13] = q3 * rn;
#pragma unroll
        for (int c = 0; c < 3; c++) m[14 + c] = acc[14 + c] * inv2;  // feat_dc
        m[17] = m2;                                                  // keep (pre-sfac)
#pragma unroll
        for (int c = 0; c < 32; c++) m[18 + c] = acc[17 + c] * inv2; // inst
#pragma unroll
        for (int c = 0; c < 16; c++) m[50 + c] = acc[49 + c] * inv2; // motion
    }
}

// ---------------- output ----------------
__global__ __launch_bounds__(256) void k_out(
        const int* __restrict__ gid, const int* __restrict__ cnt,
        const float* __restrict__ keep, const float* __restrict__ center,
        const float* __restrict__ offsetp, const float* __restrict__ opacity,
        const float* __restrict__ scale, const float* __restrict__ rot,
        const float* __restrict__ fd, const float* __restrict__ inst,
        const float* __restrict__ motion,
        const float* __restrict__ mc1g, const float* __restrict__ m2g,
        const int* __restrict__ repg, const float* __restrict__ merged,
        float* __restrict__ out) {
    int i = blockIdx.x * 256 + threadIdx.x;
    int id = gid[i];
    float* o = out + (long)i * 66;
    bool act = false; int seg = 0;
    float cx = center[3 * i + 0], cy = center[3 * i + 1], cz = center[3 * i + 2];
    if (id >= 0) {
        seg = (i / kSlab) * kNT + id;
        if (cnt[seg] >= 2) {
            float d0 = cx - mc1g[3 * seg + 0];
            float d1 = cy - mc1g[3 * seg + 1];
            float d2 = cz - mc1g[3 * seg + 2];
            act = sqrtf(d0 * d0 + d1 * d1 + d2 * d2) <= 2.0f;
        }
    }
    if (act) {
        const float* m = merged + (long)seg * 66;
        float sfac = (i == repg[seg]) ? 1.0f : 0.05f;
#pragma unroll
        for (int c = 0; c < 66; c++) {
            float v = m[c];
            if (c == 6 || c == 17) v *= sfac;
            o[c] = v;
        }
    } else {
        o[0] = cx; o[1] = cy; o[2] = cz;
#pragma unroll
        for (int c = 0; c < 3; c++) o[3 + c] = offsetp[3 * i + c];
        o[6] = opacity[i];
#pragma unroll
        for (int c = 0; c < 3; c++) o[7 + c] = scale[3 * i + c];
        float4 r4 = *(const float4*)(rot + 4 * i);
        o[10] = r4.x; o[11] = r4.y; o[12] = r4.z; o[13] = r4.w;
#pragma unroll
        for (int c = 0; c < 3; c++) o[14 + c] = fd[3 * i + c];
        o[17] = keep[i];
        const float4* ip = (const float4*)(inst + 32 * i);
#pragma unroll
        for (int q = 0; q < 8; q++) {
            float4 v = ip[q];
            o[18 + 4 * q + 0] = v.x; o[18 + 4 * q + 1] = v.y;
            o[18 + 4 * q + 2] = v.z; o[18 + 4 * q + 3] = v.w;
        }
        const float4* mp = (const float4*)(motion + 16 * i);
#pragma unroll
        for (int q = 0; q < 4; q++) {
            float4 v = mp[q];
            o[50 + 4 * q + 0] = v.x; o[50 + 4 * q + 1] = v.y;
            o[50 + 4 * q + 2] = v.z; o[50 + 4 * q + 3] = v.w;
        }
    }
}

extern "C" void kernel_launch(void* const* d_in, const int* in_sizes, int n_in,
                              void* d_out, int out_size, void* d_ws, size_t ws_size,
                              hipStream_t stream) {
    const float* center = (const float*)d_in[0];
    const float* offsetp = (const float*)d_in[1];
    const float* opacity = (const float*)d_in[2];
    const float* scale = (const float*)d_in[3];
    const float* rot = (const float*)d_in[4];
    const float* fd = (const float*)d_in[5];
    const float* keep = (const float*)d_in[6];
    const float* inst = (const float*)d_in[7];
    const float* motion = (const float*)d_in[8];
    const int* gid = (const int*)d_in[9];
    float* out = (float*)d_out;

    // workspace layout (4-byte units)
    int* cnt      = (int*)d_ws;                    // [0, 4096)
    int* offs     = (int*)d_ws + 4096;             // [4096, 8192)
    int* cursor   = (int*)d_ws + 8192;             // [8192, 12288)
    float* mc1g   = (float*)d_ws + 12288;          // [12288, 24576)
    float* m2g    = (float*)d_ws + 24576;          // [24576, 28672)
    int* repg     = (int*)d_ws + 28672;            // [28672, 32768)
    float* merged = (float*)d_ws + 32768;          // [32768, 303104)  66*4096
    int* lists    = (int*)d_ws + 303104;           // [303104, 1040384) BN ints

    hipMemsetAsync(cnt, 0, (size_t)kNSeg * 4, stream);

    k_count<<<kBN / kChunk, 1024, 0, stream>>>(gid, cnt);
    k_scan<<<1, 1024, 0, stream>>>(cnt, offs, cursor);
    k_fill<<<kBN / kChunk, 1024, 0, stream>>>(gid, cursor, lists);
    k_seg<<<kNSeg, 256, 0, stream>>>(lists, offs, cnt, keep, center, offsetp, opacity,
                                     scale, rot, fd, inst, motion, mc1g, m2g, repg, merged);
    k_out<<<kBN / 256, 256, 0, stream>>>(gid, cnt, keep, center, offsetp, opacity, scale,
                                         rot, fd, inst, motion, mc1g, m2g, repg, merged, out);
}